// Round 1
// baseline (119.919 us; speedup 1.0000x reference)
//
#include <hip/hip_runtime.h>
#include <math.h>

// Problem constants (from reference):
//   features: (1, 50, 50, 1024) fp32, NHWC (channels contiguous)
//   boxes:    (1, 300, 4) fp32, [y1, x1, y2, x2], sorted so y2>=y1, x2>=x1, in [0,1]
//   CROP=14, POOL_K=2  ->  output (1, 300, 7, 7, 1024) fp32
#define FH 50
#define FW 50
#define FC 1024
#define NBOX 300
#define CROPSZ 14
#define PO 7   // pooled size = CROP/POOL_K

// One block per (box, pooled cell). 256 threads x float4 = 1024 channels.
__global__ __launch_bounds__(256) void roi_pool_kernel(
    const float* __restrict__ feat,    // (50,50,1024)
    const float* __restrict__ boxes,   // (300,4)
    float* __restrict__ out)           // (300,7,7,1024)
{
    const int pxy = blockIdx.x;        // 0..48  (py*7+px)
    const int n   = blockIdx.y;        // 0..299
    const int py  = pxy / PO;
    const int px  = pxy - py * PO;
    const int c4  = threadIdx.x;       // 0..255 -> channels [4*c4, 4*c4+4)

    // Box coords — block-uniform, compiler emits scalar loads.
    const float by1 = boxes[n * 4 + 0];
    const float bx1 = boxes[n * 4 + 1];
    const float by2 = boxes[n * 4 + 2];
    const float bx2 = boxes[n * 4 + 3];

    // ys = y1*(H-1) + iy * (y2-y1)*(H-1)/(CROP-1)
    const float stepy = (by2 - by1) * (49.0f / 13.0f);
    const float stepx = (bx2 - bx1) * (49.0f / 13.0f);
    const float basey = by1 * 49.0f;
    const float basex = bx1 * 49.0f;

    const float4* __restrict__ f4 = reinterpret_cast<const float4*>(feat);

    float4 m;
    m.x = -INFINITY; m.y = -INFINITY; m.z = -INFINITY; m.w = -INFINITY;

    #pragma unroll
    for (int dy = 0; dy < 2; ++dy) {
        const int iy = py * 2 + dy;
        const float ys  = basey + (float)iy * stepy;
        const float y0f = floorf(ys);
        const float wy  = ys - y0f;              // unclipped floor for the weight
        int y0 = (int)y0f;
        y0 = min(max(y0, 0), FH - 1);
        const int y1i = min(y0 + 1, FH - 1);

        #pragma unroll
        for (int dx = 0; dx < 2; ++dx) {
            const int ix = px * 2 + dx;
            const float xs  = basex + (float)ix * stepx;
            const float x0f = floorf(xs);
            const float wx  = xs - x0f;
            int x0 = (int)x0f;
            x0 = min(max(x0, 0), FW - 1);
            const int x1i = min(x0 + 1, FW - 1);

            const int rT = y0  * FW;
            const int rB = y1i * FW;
            const float4 tl = f4[(rT + x0 ) * (FC / 4) + c4];
            const float4 tr = f4[(rT + x1i) * (FC / 4) + c4];
            const float4 bl = f4[(rB + x0 ) * (FC / 4) + c4];
            const float4 br = f4[(rB + x1i) * (FC / 4) + c4];

            // top = tl + (tr-tl)*wx ; bot = bl + (br-bl)*wx ; v = top + (bot-top)*wy
            float4 v;
            {
                const float tx = tl.x + (tr.x - tl.x) * wx;
                const float bx_ = bl.x + (br.x - bl.x) * wx;
                v.x = tx + (bx_ - tx) * wy;
            }
            {
                const float ty = tl.y + (tr.y - tl.y) * wx;
                const float by_ = bl.y + (br.y - bl.y) * wx;
                v.y = ty + (by_ - ty) * wy;
            }
            {
                const float tz = tl.z + (tr.z - tl.z) * wx;
                const float bz_ = bl.z + (br.z - bl.z) * wx;
                v.z = tz + (bz_ - tz) * wy;
            }
            {
                const float tw = tl.w + (tr.w - tl.w) * wx;
                const float bw_ = bl.w + (br.w - bl.w) * wx;
                v.w = tw + (bw_ - tw) * wy;
            }

            m.x = fmaxf(m.x, v.x);
            m.y = fmaxf(m.y, v.y);
            m.z = fmaxf(m.z, v.z);
            m.w = fmaxf(m.w, v.w);
        }
    }

    float4* __restrict__ o4 = reinterpret_cast<float4*>(out);
    o4[(n * (PO * PO) + pxy) * (FC / 4) + c4] = m;
}

extern "C" void kernel_launch(void* const* d_in, const int* in_sizes, int n_in,
                              void* d_out, int out_size, void* d_ws, size_t ws_size,
                              hipStream_t stream) {
    const float* feat  = (const float*)d_in[0];  // (1,50,50,1024)
    const float* boxes = (const float*)d_in[1];  // (1,300,4)
    float* out = (float*)d_out;                  // (1,300,7,7,1024)

    dim3 grid(PO * PO, NBOX);
    dim3 block(256);
    roi_pool_kernel<<<grid, block, 0, stream>>>(feat, boxes, out);
}

// Round 2
// 109.726 us; speedup vs baseline: 1.0929x; 1.0929x over previous
//
#include <hip/hip_runtime.h>
#include <math.h>

// features: (1,50,50,1024) fp32 NHWC; boxes: (1,300,4) [y1,x1,y2,x2] in [0,1]
// CROP=14, POOL_K=2 -> out (1,300,7,7,1024) fp32
#define FH 50
#define FW 50
#define FC4 256    // float4s per pixel (1024 ch / 4)
#define NBOX 300
#define PO 7

typedef float nat4 __attribute__((ext_vector_type(4)));

__device__ __forceinline__ nat4 lerp4(nat4 a, nat4 b, float w) {
    return a + (b - a) * w;
}
__device__ __forceinline__ nat4 max4(nat4 a, nat4 b) {
    nat4 r;
    r.x = fmaxf(a.x, b.x);
    r.y = fmaxf(a.y, b.y);
    r.z = fmaxf(a.z, b.z);
    r.w = fmaxf(a.w, b.w);
    return r;
}

// One block per (box, pooled row). 256 threads x float4 = 1024 channels.
// Grid is XCD-swizzled: block i -> XCD i%8 (round-robin heuristic), and we
// map so all 7 row-strips of a box land on the same XCD for L2 reuse.
__global__ __launch_bounds__(256) void roi_pool_kernel(
    const float* __restrict__ feat,    // (50,50,1024)
    const float* __restrict__ boxes,   // (300,4)
    float* __restrict__ out)           // (300,7,7,1024)
{
    const int j = blockIdx.x & 7;      // XCD slot
    const int k = blockIdx.x >> 3;     // 0..265
    const int n = j + 8 * (k / PO);    // box: all py of box n share XCD n%8
    const int py = k % PO;
    if (n >= NBOX) return;
    const int c4 = threadIdx.x;        // channel float4 index 0..255

    // Box coords — block-uniform.
    const float by1 = boxes[n * 4 + 0];
    const float bx1 = boxes[n * 4 + 1];
    const float by2 = boxes[n * 4 + 2];
    const float bx2 = boxes[n * 4 + 3];

    const float stepy = (by2 - by1) * (49.0f / 13.0f);
    const float stepx = (bx2 - bx1) * (49.0f / 13.0f);
    const float basey = by1 * 49.0f;
    const float basex = bx1 * 49.0f;

    // Two crop rows for this pooled row: iy = 2*py, 2*py+1.
    const float ysA = basey + (float)(2 * py) * stepy;
    const float ysB = ysA + stepy;
    const float fA = floorf(ysA); const float wyA = ysA - fA;
    const float fB = floorf(ysB); const float wyB = ysB - fB;
    int y0A = min(max((int)fA, 0), FH - 1); const int y1A = min(y0A + 1, FH - 1);
    int y0B = min(max((int)fB, 0), FH - 1); const int y1B = min(y0B + 1, FH - 1);

    const nat4* __restrict__ f4 = reinterpret_cast<const nat4*>(feat);
    const int rA0 = y0A * FW, rA1 = y1A * FW, rB0 = y0B * FW, rB1 = y1B * FW;

    // Register column-cache: values at cols (cc, min(cc+1,49)) for 4 rows.
    int cc = -1000;
    nat4 A00, A01, A10, A11, B00, B01, B10, B11;
    // silence may-be-uninitialized; first iteration always takes full-load path
    A00 = A01 = A10 = A11 = B00 = B01 = B10 = B11 = (nat4)0.0f;

    nat4 m = (nat4)(-INFINITY);

    nat4* __restrict__ o4 = reinterpret_cast<nat4*>(out);
    nat4* __restrict__ obase = o4 + (size_t)(n * (PO * PO) + py * PO) * FC4 + c4;

    for (int ix = 0; ix < 2 * PO; ++ix) {
        const float xs = basex + (float)ix * stepx;
        const float xf = floorf(xs);
        const float wx = xs - xf;
        int x0 = min(max((int)xf, 0), FW - 1);
        const int x1 = min(x0 + 1, FW - 1);

        if (x0 != cc) {                 // block-uniform branch
            if (x0 == cc + 1) {
                // shift: cached col1 (== cc+1 == x0) becomes col0; load new col1
                A00 = A01; A10 = A11; B00 = B01; B10 = B11;
                A01 = f4[(rA0 + x1) * FC4 + c4];
                A11 = f4[(rA1 + x1) * FC4 + c4];
                B01 = f4[(rB0 + x1) * FC4 + c4];
                B11 = f4[(rB1 + x1) * FC4 + c4];
            } else {
                A00 = f4[(rA0 + x0) * FC4 + c4];
                A01 = f4[(rA0 + x1) * FC4 + c4];
                A10 = f4[(rA1 + x0) * FC4 + c4];
                A11 = f4[(rA1 + x1) * FC4 + c4];
                B00 = f4[(rB0 + x0) * FC4 + c4];
                B01 = f4[(rB0 + x1) * FC4 + c4];
                B10 = f4[(rB1 + x0) * FC4 + c4];
                B11 = f4[(rB1 + x1) * FC4 + c4];
            }
            cc = x0;
        }

        const nat4 vA = lerp4(lerp4(A00, A01, wx), lerp4(A10, A11, wx), wyA);
        const nat4 vB = lerp4(lerp4(B00, B01, wx), lerp4(B10, B11, wx), wyB);
        m = max4(m, max4(vA, vB));

        if (ix & 1) {
            // output is write-once, never re-read: keep it out of L2 so the
            // feature map stays resident
            __builtin_nontemporal_store(m, obase + (ix >> 1) * FC4);
            m = (nat4)(-INFINITY);
        }
    }
}

extern "C" void kernel_launch(void* const* d_in, const int* in_sizes, int n_in,
                              void* d_out, int out_size, void* d_ws, size_t ws_size,
                              hipStream_t stream) {
    const float* feat  = (const float*)d_in[0];  // (1,50,50,1024)
    const float* boxes = (const float*)d_in[1];  // (1,300,4)
    float* out = (float*)d_out;                  // (1,300,7,7,1024)

    // 8 XCD slots x ceil(300/8)=38 boxes x 7 pooled rows = 2128 blocks
    dim3 grid(8 * 38 * PO);
    dim3 block(256);
    roi_pool_kernel<<<grid, block, 0, stream>>>(feat, boxes, out);
}